// Round 1
// baseline (403.081 us; speedup 1.0000x reference)
//
#include <hip/hip_runtime.h>
#include <hip/hip_bf16.h>
#include <math.h>

#define B_N 8
#define S_N 2048
#define C_N 384
#define D_N 64

// 4x4 outer-product accumulate: Sm[a][c] += Av[a] * Bv[c]
#define OUTER4(Sm, Av, Bv) do { \
  Sm[0][0] = fmaf(Av.x, Bv.x, Sm[0][0]); \
  Sm[0][1] = fmaf(Av.x, Bv.y, Sm[0][1]); \
  Sm[0][2] = fmaf(Av.x, Bv.z, Sm[0][2]); \
  Sm[0][3] = fmaf(Av.x, Bv.w, Sm[0][3]); \
  Sm[1][0] = fmaf(Av.y, Bv.x, Sm[1][0]); \
  Sm[1][1] = fmaf(Av.y, Bv.y, Sm[1][1]); \
  Sm[1][2] = fmaf(Av.y, Bv.z, Sm[1][2]); \
  Sm[1][3] = fmaf(Av.y, Bv.w, Sm[1][3]); \
  Sm[2][0] = fmaf(Av.z, Bv.x, Sm[2][0]); \
  Sm[2][1] = fmaf(Av.z, Bv.y, Sm[2][1]); \
  Sm[2][2] = fmaf(Av.z, Bv.z, Sm[2][2]); \
  Sm[2][3] = fmaf(Av.z, Bv.w, Sm[2][3]); \
  Sm[3][0] = fmaf(Av.w, Bv.x, Sm[3][0]); \
  Sm[3][1] = fmaf(Av.w, Bv.y, Sm[3][1]); \
  Sm[3][2] = fmaf(Av.w, Bv.z, Sm[3][2]); \
  Sm[3][3] = fmaf(Av.w, Bv.w, Sm[3][3]); \
} while (0)

// ---------------------------------------------------------------------------
// Kernel 1: QKV projection. Block = 16 rows of x staged in LDS, 192 threads:
// thread t -> matrix (t/64) in {Q,K,V}, output dim d = t%64.
// Q is stored pre-scaled by 1/sqrt(64) = 0.125.
// ---------------------------------------------------------------------------
__global__ __launch_bounds__(192) void qkv_proj(
    const float* __restrict__ x,
    const float* __restrict__ Wq, const float* __restrict__ Wk,
    const float* __restrict__ Wv,
    float* __restrict__ Q, float* __restrict__ K, float* __restrict__ V) {
  __shared__ float xs[16 * C_N];
  const int t = threadIdx.x;
  const int row0 = blockIdx.x * 16;               // flat row in [0, B*S)
  const float* xb = x + (size_t)row0 * C_N;       // 16 contiguous rows
  for (int idx = t; idx < 16 * C_N; idx += 192) xs[idx] = xb[idx];
  __syncthreads();

  const int mat = t >> 6;                         // 0=Q 1=K 2=V (wave-aligned)
  const int d = t & 63;
  const float* W = (mat == 0) ? Wq : (mat == 1) ? Wk : Wv;

  float acc[16];
#pragma unroll
  for (int r = 0; r < 16; ++r) acc[r] = 0.f;

  for (int c = 0; c < C_N; c += 4) {
    const float w0 = W[(c + 0) * 64 + d];
    const float w1 = W[(c + 1) * 64 + d];
    const float w2 = W[(c + 2) * 64 + d];
    const float w3 = W[(c + 3) * 64 + d];
#pragma unroll
    for (int r = 0; r < 16; ++r) {
      const float4 xv = *reinterpret_cast<const float4*>(&xs[r * C_N + c]);
      acc[r] = fmaf(xv.x, w0, acc[r]);
      acc[r] = fmaf(xv.y, w1, acc[r]);
      acc[r] = fmaf(xv.z, w2, acc[r]);
      acc[r] = fmaf(xv.w, w3, acc[r]);
    }
  }

  float* outp = (mat == 0) ? Q : (mat == 1) ? K : V;
  const float scl = (mat == 0) ? 0.125f : 1.0f;   // fold score scale into Q
#pragma unroll
  for (int r = 0; r < 16; ++r) outp[(size_t)(row0 + r) * 64 + d] = acc[r] * scl;
}

// ---------------------------------------------------------------------------
// Kernel 2: per-column softmax stats (softmax is over the QUERY axis).
// Block (jb, b): owns 64 columns j0..j0+63; scans row blocks i0 = j0..2047
// with an online (max, sum) update held in LDS. 256 threads as 16x16,
// each computing a 4x4 score sub-tile via transposed-LDS outer products.
// ---------------------------------------------------------------------------
__global__ __launch_bounds__(256) void col_stats(
    const float* __restrict__ Q, const float* __restrict__ K,
    float* __restrict__ m_out, float* __restrict__ rz_out) {
  const int jb = blockIdx.x;
  const int b  = blockIdx.y;
  const int j0 = jb * 64;
  const int t  = threadIdx.x;
  const int tx = t & 15;          // column group (4 cols)
  const int ty = t >> 4;          // row group (4 rows), 0..15
  const int wave = t >> 6;        // 0..3
  const int lane = t & 63;

  __shared__ float kT[64][68];    // kT[d][j]
  __shared__ float qT[64][68];    // qT[d][r]
  __shared__ float m_l[64], z_l[64], f_l[64];
  __shared__ float smax[4][64], ssum[4][64];

  const float* Kb = K + ((size_t)b * S_N + j0) * 64;
  const float* Qb = Q + (size_t)b * S_N * 64;

  {
    const int lr = t >> 6, ld = t & 63;
    for (int rr = lr; rr < 64; rr += 4) kT[ld][rr] = Kb[rr * 64 + ld];
  }
  if (t < 64) { m_l[t] = -__builtin_inff(); z_l[t] = 0.f; }
  __syncthreads();

  for (int i0 = j0; i0 < S_N; i0 += 64) {
    {  // stage 64 q rows transposed
      const int lr = t >> 6, ld = t & 63;
      for (int rr = lr; rr < 64; rr += 4) qT[ld][rr] = Qb[(size_t)(i0 + rr) * 64 + ld];
    }
    __syncthreads();

    float s[4][4];
#pragma unroll
    for (int a = 0; a < 4; ++a)
#pragma unroll
      for (int c2 = 0; c2 < 4; ++c2) s[a][c2] = 0.f;

#pragma unroll 4
    for (int d = 0; d < 64; ++d) {
      const float4 q4 = *reinterpret_cast<const float4*>(&qT[d][ty * 4]);
      const float4 k4 = *reinterpret_cast<const float4*>(&kT[d][tx * 4]);
      OUTER4(s, q4, k4);
    }

    if (i0 == j0) {  // only the diagonal block is partially masked
#pragma unroll
      for (int a = 0; a < 4; ++a)
#pragma unroll
        for (int c2 = 0; c2 < 4; ++c2) {
          if (ty * 4 + a < tx * 4 + c2) s[a][c2] = -__builtin_inff();
        }
    }

    // per-thread column max over its 4 rows, then wave-reduce over ty%4
    float pm[4];
#pragma unroll
    for (int c2 = 0; c2 < 4; ++c2) {
      pm[c2] = fmaxf(fmaxf(s[0][c2], s[1][c2]), fmaxf(s[2][c2], s[3][c2]));
      pm[c2] = fmaxf(pm[c2], __shfl_xor(pm[c2], 16));
      pm[c2] = fmaxf(pm[c2], __shfl_xor(pm[c2], 32));
    }
    if (lane < 16) {
#pragma unroll
      for (int c2 = 0; c2 < 4; ++c2) smax[wave][tx * 4 + c2] = pm[c2];
    }
    __syncthreads();

    if (t < 64) {
      const float bm = fmaxf(fmaxf(smax[0][t], smax[1][t]),
                             fmaxf(smax[2][t], smax[3][t]));
      const float mo = m_l[t];
      const float mn = fmaxf(mo, bm);
      f_l[t] = __expf(mo - mn);   // 0 when mo = -inf
      m_l[t] = mn;
    }
    __syncthreads();

    float ps[4];
#pragma unroll
    for (int c2 = 0; c2 < 4; ++c2) {
      const float mn = m_l[tx * 4 + c2];
      ps[c2] = __expf(s[0][c2] - mn) + __expf(s[1][c2] - mn) +
               __expf(s[2][c2] - mn) + __expf(s[3][c2] - mn);
      ps[c2] += __shfl_xor(ps[c2], 16);
      ps[c2] += __shfl_xor(ps[c2], 32);
    }
    if (lane < 16) {
#pragma unroll
      for (int c2 = 0; c2 < 4; ++c2) ssum[wave][tx * 4 + c2] = ps[c2];
    }
    __syncthreads();

    if (t < 64) {
      z_l[t] = z_l[t] * f_l[t] + (ssum[0][t] + ssum[1][t] + ssum[2][t] + ssum[3][t]);
    }
    __syncthreads();  // also guards qT overwrite next iteration
  }

  if (t < 64) {
    m_out[(size_t)b * S_N + j0 + t] = m_l[t];
    rz_out[(size_t)b * S_N + j0 + t] = 1.0f / z_l[t];
  }
}

// ---------------------------------------------------------------------------
// Kernel 3: output pass. Grid (jchunk, ib, b); each WG recomputes scores for
// its 64-row Q tile against <=8 K blocks, forms P = exp(s - m_j) / Z_j, and
// accumulates P @ V. Partial results combined across j-chunks via atomicAdd
// (the column-normalized weights make the j-sum fully associative).
// ---------------------------------------------------------------------------
__global__ __launch_bounds__(256) void attn_out(
    const float* __restrict__ Q, const float* __restrict__ K,
    const float* __restrict__ V, const float* __restrict__ m_arr,
    const float* __restrict__ rz_arr, float* __restrict__ out) {
  const int b  = blockIdx.z;
  const int ib = blockIdx.y;
  const int jb_lo = blockIdx.x * 8;
  if (jb_lo > ib) return;                 // whole block exits: no barrier hazard
  const int jb_hi = min(jb_lo + 8, ib + 1);

  const int t  = threadIdx.x;
  const int tx = t & 15;
  const int ty = t >> 4;

  __shared__ float qT[64][68];   // qT[d][r]
  __shared__ float kT[64][68];   // kT[d][j]
  __shared__ float vv[64][68];   // vv[j][d]
  __shared__ float PT[64][68];   // PT[j][r]
  __shared__ float m_l[64], rz_l[64];

  const int i0 = ib * 64;
  const float* Qb = Q + ((size_t)b * S_N + i0) * 64;
  const float* Kb = K + (size_t)b * S_N * 64;
  const float* Vb = V + (size_t)b * S_N * 64;

  {
    const int lr = t >> 6, ld = t & 63;
    for (int rr = lr; rr < 64; rr += 4) qT[ld][rr] = Qb[rr * 64 + ld];
  }

  float acc[4][4];
#pragma unroll
  for (int a = 0; a < 4; ++a)
#pragma unroll
    for (int c2 = 0; c2 < 4; ++c2) acc[a][c2] = 0.f;

  for (int jb = jb_lo; jb < jb_hi; ++jb) {
    const int j0 = jb * 64;
    __syncthreads();  // protect kT/vv/PT (prev iter reads) and qT (first iter)
    {
      const int lr = t >> 6, ld = t & 63;
      for (int rr = lr; rr < 64; rr += 4) {
        kT[ld][rr] = Kb[(size_t)(j0 + rr) * 64 + ld];
        vv[rr][ld] = Vb[(size_t)(j0 + rr) * 64 + ld];
      }
    }
    if (t < 64) {
      m_l[t]  = m_arr[(size_t)b * S_N + j0 + t];
      rz_l[t] = rz_arr[(size_t)b * S_N + j0 + t];
    }
    __syncthreads();

    float s[4][4];
#pragma unroll
    for (int a = 0; a < 4; ++a)
#pragma unroll
      for (int c2 = 0; c2 < 4; ++c2) s[a][c2] = 0.f;

#pragma unroll 4
    for (int d = 0; d < 64; ++d) {
      const float4 q4 = *reinterpret_cast<const float4*>(&qT[d][ty * 4]);
      const float4 k4 = *reinterpret_cast<const float4*>(&kT[d][tx * 4]);
      OUTER4(s, q4, k4);
    }

    // P = exp(s - m_j) * (1/Z_j), causal-masked; stage transposed for PV
#pragma unroll
    for (int c2 = 0; c2 < 4; ++c2) {
      const float mn = m_l[tx * 4 + c2];
      const float rz = rz_l[tx * 4 + c2];
      const int jcol = j0 + tx * 4 + c2;
#pragma unroll
      for (int a = 0; a < 4; ++a) {
        const int irow = i0 + ty * 4 + a;
        const float p = (jcol <= irow) ? __expf(s[a][c2] - mn) * rz : 0.f;
        PT[tx * 4 + c2][ty * 4 + a] = p;
      }
    }
    __syncthreads();

#pragma unroll 4
    for (int j = 0; j < 64; ++j) {
      const float4 p4 = *reinterpret_cast<const float4*>(&PT[j][ty * 4]);
      const float4 v4 = *reinterpret_cast<const float4*>(&vv[j][tx * 4]);
      OUTER4(acc, p4, v4);
    }
  }

#pragma unroll
  for (int a = 0; a < 4; ++a)
#pragma unroll
    for (int c2 = 0; c2 < 4; ++c2) {
      atomicAdd(&out[((size_t)b * S_N + i0 + ty * 4 + a) * D_N + tx * 4 + c2],
                acc[a][c2]);
    }
}

extern "C" void kernel_launch(void* const* d_in, const int* in_sizes, int n_in,
                              void* d_out, int out_size, void* d_ws, size_t ws_size,
                              hipStream_t stream) {
  (void)in_sizes; (void)n_in; (void)ws_size;
  const float* x  = (const float*)d_in[0];
  const float* Wq = (const float*)d_in[1];
  const float* Wk = (const float*)d_in[2];
  const float* Wv = (const float*)d_in[3];
  float* out = (float*)d_out;

  float* Qp = (float*)d_ws;                    // [B,S,64] pre-scaled
  float* Kp = Qp + (size_t)B_N * S_N * D_N;    // [B,S,64]
  float* Vp = Kp + (size_t)B_N * S_N * D_N;    // [B,S,64]
  float* mC = Vp + (size_t)B_N * S_N * D_N;    // [B,S] column max
  float* rZ = mC + (size_t)B_N * S_N;          // [B,S] 1/column sum

  hipMemsetAsync(d_out, 0, (size_t)out_size * sizeof(float), stream);

  qkv_proj<<<dim3(B_N * S_N / 16), dim3(192), 0, stream>>>(x, Wq, Wk, Wv, Qp, Kp, Vp);
  col_stats<<<dim3(S_N / 64, B_N), dim3(256), 0, stream>>>(Qp, Kp, mC, rZ);
  attn_out<<<dim3(4, S_N / 64, B_N), dim3(256), 0, stream>>>(Qp, Kp, Vp, mC, rZ, out);
}

// Round 4
// 289.756 us; speedup vs baseline: 1.3911x; 1.3911x over previous
//
#include <hip/hip_runtime.h>
#include <hip/hip_bf16.h>
#include <math.h>

#define B_N 8
#define S_N 2048
#define C_N 384
#define D_N 64
#define NCHUNK 8          // i-chunks for col_part (256 rows each)
#define JCH 4             // jb blocks per attn_out WG

// 4x4 outer-product accumulate: Sm[a][c] += Av[a] * Bv[c]
#define OUTER4(Sm, Av, Bv) do { \
  Sm[0][0] = fmaf(Av.x, Bv.x, Sm[0][0]); \
  Sm[0][1] = fmaf(Av.x, Bv.y, Sm[0][1]); \
  Sm[0][2] = fmaf(Av.x, Bv.z, Sm[0][2]); \
  Sm[0][3] = fmaf(Av.x, Bv.w, Sm[0][3]); \
  Sm[1][0] = fmaf(Av.y, Bv.x, Sm[1][0]); \
  Sm[1][1] = fmaf(Av.y, Bv.y, Sm[1][1]); \
  Sm[1][2] = fmaf(Av.y, Bv.z, Sm[1][2]); \
  Sm[1][3] = fmaf(Av.y, Bv.w, Sm[1][3]); \
  Sm[2][0] = fmaf(Av.z, Bv.x, Sm[2][0]); \
  Sm[2][1] = fmaf(Av.z, Bv.y, Sm[2][1]); \
  Sm[2][2] = fmaf(Av.z, Bv.z, Sm[2][2]); \
  Sm[2][3] = fmaf(Av.z, Bv.w, Sm[2][3]); \
  Sm[3][0] = fmaf(Av.w, Bv.x, Sm[3][0]); \
  Sm[3][1] = fmaf(Av.w, Bv.y, Sm[3][1]); \
  Sm[3][2] = fmaf(Av.w, Bv.z, Sm[3][2]); \
  Sm[3][3] = fmaf(Av.w, Bv.w, Sm[3][3]); \
} while (0)

// ---------------------------------------------------------------------------
// Kernel 1: QKV projection (unchanged from R0). 16 x-rows/block, 192 threads.
// Q is stored pre-scaled by 1/sqrt(64) = 0.125.
// ---------------------------------------------------------------------------
__global__ __launch_bounds__(192) void qkv_proj(
    const float* __restrict__ x,
    const float* __restrict__ Wq, const float* __restrict__ Wk,
    const float* __restrict__ Wv,
    float* __restrict__ Q, float* __restrict__ K, float* __restrict__ V) {
  __shared__ float xs[16 * C_N];
  const int t = threadIdx.x;
  const int row0 = blockIdx.x * 16;
  const float* xb = x + (size_t)row0 * C_N;
  for (int idx = t; idx < 16 * C_N; idx += 192) xs[idx] = xb[idx];
  __syncthreads();

  const int mat = t >> 6;
  const int d = t & 63;
  const float* W = (mat == 0) ? Wq : (mat == 1) ? Wk : Wv;

  float acc[16];
#pragma unroll
  for (int r = 0; r < 16; ++r) acc[r] = 0.f;

  for (int c = 0; c < C_N; c += 4) {
    const float w0 = W[(c + 0) * 64 + d];
    const float w1 = W[(c + 1) * 64 + d];
    const float w2 = W[(c + 2) * 64 + d];
    const float w3 = W[(c + 3) * 64 + d];
#pragma unroll
    for (int r = 0; r < 16; ++r) {
      const float4 xv = *reinterpret_cast<const float4*>(&xs[r * C_N + c]);
      acc[r] = fmaf(xv.x, w0, acc[r]);
      acc[r] = fmaf(xv.y, w1, acc[r]);
      acc[r] = fmaf(xv.z, w2, acc[r]);
      acc[r] = fmaf(xv.w, w3, acc[r]);
    }
  }

  float* outp = (mat == 0) ? Q : (mat == 1) ? K : V;
  const float scl = (mat == 0) ? 0.125f : 1.0f;
#pragma unroll
  for (int r = 0; r < 16; ++r) outp[(size_t)(row0 + r) * 64 + d] = acc[r] * scl;
}

// ---------------------------------------------------------------------------
// Kernel 2a: partial column stats. Grid (jb, ic, b). Each WG covers 64 cols
// and row-chunk [ic*256, (ic+1)*256) ∩ [j0, S). Writes partial (max, sum)
// per column: mP/zP[((b*32+jb)*NCHUNK+ic)*64 + j].
// ---------------------------------------------------------------------------
__global__ __launch_bounds__(256) void col_part(
    const float* __restrict__ Q, const float* __restrict__ K,
    float* __restrict__ mP, float* __restrict__ zP) {
  const int jb = blockIdx.x;
  const int ic = blockIdx.y;
  const int b  = blockIdx.z;
  const int j0 = jb * 64;
  const int t  = threadIdx.x;

  const int iStart = max(j0, ic * 256);
  const int iEnd   = min(S_N, (ic + 1) * 256);
  const size_t pbase = ((size_t)(b * 32 + jb) * NCHUNK + ic) * 64;

  if (iStart >= iEnd) {            // empty chunk: neutral partials, whole WG exits
    if (t < 64) { mP[pbase + t] = -__builtin_inff(); zP[pbase + t] = 0.f; }
    return;
  }

  const int tx = t & 15;
  const int ty = t >> 4;
  const int wave = t >> 6;
  const int lane = t & 63;

  __shared__ float kT[64][68];
  __shared__ float qT[64][68];
  __shared__ float m_l[64], z_l[64], f_l[64];
  __shared__ float smax[4][64], ssum[4][64];

  const float* Kb = K + ((size_t)b * S_N + j0) * 64;
  const float* Qb = Q + (size_t)b * S_N * 64;

  {
    const int lr = t >> 6, ld = t & 63;
    for (int rr = lr; rr < 64; rr += 4) kT[ld][rr] = Kb[rr * 64 + ld];
  }
  if (t < 64) { m_l[t] = -__builtin_inff(); z_l[t] = 0.f; }
  __syncthreads();

  for (int i0 = iStart; i0 < iEnd; i0 += 64) {
    {
      const int lr = t >> 6, ld = t & 63;
      for (int rr = lr; rr < 64; rr += 4) qT[ld][rr] = Qb[(size_t)(i0 + rr) * 64 + ld];
    }
    __syncthreads();

    float s[4][4];
#pragma unroll
    for (int a = 0; a < 4; ++a)
#pragma unroll
      for (int c2 = 0; c2 < 4; ++c2) s[a][c2] = 0.f;

#pragma unroll 4
    for (int d = 0; d < 64; ++d) {
      const float4 q4 = *reinterpret_cast<const float4*>(&qT[d][ty * 4]);
      const float4 k4 = *reinterpret_cast<const float4*>(&kT[d][tx * 4]);
      OUTER4(s, q4, k4);
    }

    if (i0 == j0) {  // diagonal block partially masked
#pragma unroll
      for (int a = 0; a < 4; ++a)
#pragma unroll
        for (int c2 = 0; c2 < 4; ++c2) {
          if (ty * 4 + a < tx * 4 + c2) s[a][c2] = -__builtin_inff();
        }
    }

    float pm[4];
#pragma unroll
    for (int c2 = 0; c2 < 4; ++c2) {
      pm[c2] = fmaxf(fmaxf(s[0][c2], s[1][c2]), fmaxf(s[2][c2], s[3][c2]));
      pm[c2] = fmaxf(pm[c2], __shfl_xor(pm[c2], 16));
      pm[c2] = fmaxf(pm[c2], __shfl_xor(pm[c2], 32));
    }
    if (lane < 16) {
#pragma unroll
      for (int c2 = 0; c2 < 4; ++c2) smax[wave][tx * 4 + c2] = pm[c2];
    }
    __syncthreads();

    if (t < 64) {
      const float bm = fmaxf(fmaxf(smax[0][t], smax[1][t]),
                             fmaxf(smax[2][t], smax[3][t]));
      const float mo = m_l[t];
      const float mn = fmaxf(mo, bm);
      f_l[t] = __expf(mo - mn);
      m_l[t] = mn;
    }
    __syncthreads();

    float ps[4];
#pragma unroll
    for (int c2 = 0; c2 < 4; ++c2) {
      const float mn = m_l[tx * 4 + c2];
      ps[c2] = __expf(s[0][c2] - mn) + __expf(s[1][c2] - mn) +
               __expf(s[2][c2] - mn) + __expf(s[3][c2] - mn);
      ps[c2] += __shfl_xor(ps[c2], 16);
      ps[c2] += __shfl_xor(ps[c2], 32);
    }
    if (lane < 16) {
#pragma unroll
      for (int c2 = 0; c2 < 4; ++c2) ssum[wave][tx * 4 + c2] = ps[c2];
    }
    __syncthreads();

    if (t < 64) {
      z_l[t] = z_l[t] * f_l[t] + (ssum[0][t] + ssum[1][t] + ssum[2][t] + ssum[3][t]);
    }
    __syncthreads();
  }

  if (t < 64) {
    mP[pbase + t] = m_l[t];
    zP[pbase + t] = z_l[t];
  }
}

// ---------------------------------------------------------------------------
// Kernel 2b: reduce the NCHUNK partials per column -> m, 1/Z.
// One thread per (b, j); 16384 threads total.
// ---------------------------------------------------------------------------
__global__ __launch_bounds__(256) void col_reduce(
    const float* __restrict__ mP, const float* __restrict__ zP,
    float* __restrict__ mC, float* __restrict__ rZ) {
  const int idx = blockIdx.x * 256 + threadIdx.x;   // b*S + j
  const int b = idx >> 11;
  const int j = idx & (S_N - 1);
  const int jb = j >> 6;
  const int jr = j & 63;
  const size_t base = (size_t)(b * 32 + jb) * NCHUNK * 64 + jr;

  float m = -__builtin_inff();
#pragma unroll
  for (int ic = 0; ic < NCHUNK; ++ic) m = fmaxf(m, mP[base + (size_t)ic * 64]);
  float z = 0.f;
#pragma unroll
  for (int ic = 0; ic < NCHUNK; ++ic)
    z += zP[base + (size_t)ic * 64] * __expf(mP[base + (size_t)ic * 64] - m);

  mC[idx] = m;
  rZ[idx] = 1.0f / z;
}

// ---------------------------------------------------------------------------
// Kernel 3: output pass. Grid (jchunk of JCH, ib, b). PT aliases kT's LDS
// (score tile dead before P written) -> 52.7 KB LDS -> 3 WGs/CU.
// ---------------------------------------------------------------------------
__global__ __launch_bounds__(256) void attn_out(
    const float* __restrict__ Q, const float* __restrict__ K,
    const float* __restrict__ V, const float* __restrict__ m_arr,
    const float* __restrict__ rz_arr, float* __restrict__ out) {
  const int b  = blockIdx.z;
  const int ib = blockIdx.y;
  const int jb_lo = blockIdx.x * JCH;
  if (jb_lo > ib) return;
  const int jb_hi = min(jb_lo + JCH, ib + 1);

  const int t  = threadIdx.x;
  const int tx = t & 15;
  const int ty = t >> 4;

  __shared__ float qT[64][68];    // qT[d][r], live whole kernel
  __shared__ float kTP[64][68];   // kT[d][j] during scores; PT[j][r] after
  __shared__ float vv[64][68];    // vv[j][d]
  __shared__ float m_l[64], rz_l[64];

  const int i0 = ib * 64;
  const float* Qb = Q + ((size_t)b * S_N + i0) * 64;
  const float* Kb = K + (size_t)b * S_N * 64;
  const float* Vb = V + (size_t)b * S_N * 64;

  {
    const int lr = t >> 6, ld = t & 63;
    for (int rr = lr; rr < 64; rr += 4) qT[ld][rr] = Qb[rr * 64 + ld];
  }

  float acc[4][4];
#pragma unroll
  for (int a = 0; a < 4; ++a)
#pragma unroll
    for (int c2 = 0; c2 < 4; ++c2) acc[a][c2] = 0.f;

  for (int jb = jb_lo; jb < jb_hi; ++jb) {
    const int j0 = jb * 64;
    __syncthreads();  // qT ready (iter 0); prev-iter PV reads done (later)
    {
      const int lr = t >> 6, ld = t & 63;
      for (int rr = lr; rr < 64; rr += 4) {
        kTP[ld][rr] = Kb[(size_t)(j0 + rr) * 64 + ld];
        vv[rr][ld]  = Vb[(size_t)(j0 + rr) * 64 + ld];
      }
    }
    if (t < 64) {
      m_l[t]  = m_arr[(size_t)b * S_N + j0 + t];
      rz_l[t] = rz_arr[(size_t)b * S_N + j0 + t];
    }
    __syncthreads();

    float s[4][4];
#pragma unroll
    for (int a = 0; a < 4; ++a)
#pragma unroll
      for (int c2 = 0; c2 < 4; ++c2) s[a][c2] = 0.f;

#pragma unroll 4
    for (int d = 0; d < 64; ++d) {
      const float4 q4 = *reinterpret_cast<const float4*>(&qT[d][ty * 4]);
      const float4 k4 = *reinterpret_cast<const float4*>(&kTP[d][tx * 4]);
      OUTER4(s, q4, k4);
    }

    // compute P in registers, then overwrite kTP with PT after a barrier
    float p[4][4];
#pragma unroll
    for (int c2 = 0; c2 < 4; ++c2) {
      const float mn = m_l[tx * 4 + c2];
      const float rz = rz_l[tx * 4 + c2];
      const int jcol = j0 + tx * 4 + c2;
#pragma unroll
      for (int a = 0; a < 4; ++a) {
        const int irow = i0 + ty * 4 + a;
        p[a][c2] = (jcol <= irow) ? __expf(s[a][c2] - mn) * rz : 0.f;
      }
    }
    __syncthreads();  // all kTP (kT) reads finished

#pragma unroll
    for (int c2 = 0; c2 < 4; ++c2)
#pragma unroll
      for (int a = 0; a < 4; ++a)
        kTP[tx * 4 + c2][ty * 4 + a] = p[a][c2];   // PT[j][r]
    __syncthreads();

#pragma unroll 4
    for (int j = 0; j < 64; ++j) {
      const float4 p4 = *reinterpret_cast<const float4*>(&kTP[j][ty * 4]);
      const float4 v4 = *reinterpret_cast<const float4*>(&vv[j][tx * 4]);
      OUTER4(acc, p4, v4);
    }
  }

#pragma unroll
  for (int a = 0; a < 4; ++a)
#pragma unroll
    for (int c2 = 0; c2 < 4; ++c2) {
      atomicAdd(&out[((size_t)b * S_N + i0 + ty * 4 + a) * D_N + tx * 4 + c2],
                acc[a][c2]);
    }
}

extern "C" void kernel_launch(void* const* d_in, const int* in_sizes, int n_in,
                              void* d_out, int out_size, void* d_ws, size_t ws_size,
                              hipStream_t stream) {
  (void)in_sizes; (void)n_in; (void)ws_size;
  const float* x  = (const float*)d_in[0];
  const float* Wq = (const float*)d_in[1];
  const float* Wk = (const float*)d_in[2];
  const float* Wv = (const float*)d_in[3];
  float* out = (float*)d_out;

  float* Qp = (float*)d_ws;                      // [B,S,64] pre-scaled
  float* Kp = Qp + (size_t)B_N * S_N * D_N;      // [B,S,64]
  float* Vp = Kp + (size_t)B_N * S_N * D_N;      // [B,S,64]
  float* mC = Vp + (size_t)B_N * S_N * D_N;      // [B,S]
  float* rZ = mC + (size_t)B_N * S_N;            // [B,S]
  float* mP = rZ + (size_t)B_N * S_N;            // [B,32,NCHUNK,64]
  float* zP = mP + (size_t)B_N * 32 * NCHUNK * 64;

  hipMemsetAsync(d_out, 0, (size_t)out_size * sizeof(float), stream);

  qkv_proj<<<dim3(B_N * S_N / 16), dim3(192), 0, stream>>>(x, Wq, Wk, Wv, Qp, Kp, Vp);
  col_part<<<dim3(S_N / 64, NCHUNK, B_N), dim3(256), 0, stream>>>(Qp, Kp, mP, zP);
  col_reduce<<<dim3(B_N * S_N / 256), dim3(256), 0, stream>>>(mP, zP, mC, rZ);
  attn_out<<<dim3(S_N / 64 / JCH, S_N / 64, B_N), dim3(256), 0, stream>>>(
      Qp, Kp, Vp, mC, rZ, out);
}

// Round 6
// 177.180 us; speedup vs baseline: 2.2750x; 1.6354x over previous
//
#include <hip/hip_runtime.h>
#include <hip/hip_bf16.h>
#include <math.h>

#define B_N 8
#define S_N 2048
#define C_N 384
#define D_N 64
#define NCHUNK 8          // i-chunks for col_part (256 rows each)
#define JCH 4             // jb blocks per attn_out WG
#define NEG_BIG (-1e30f)

typedef __bf16 bf16x8 __attribute__((ext_vector_type(8)));
typedef float f32x4 __attribute__((ext_vector_type(4)));

static __device__ __forceinline__ bf16x8 ldfrag(const __bf16* p) {
  return *reinterpret_cast<const bf16x8*>(p);
}

// ---------------------------------------------------------------------------
// Kernel 1: QKV projection, f32 VALU compute, bf16 outputs.
// Q pre-scaled by 0.125. V stored TRANSPOSED: Vt[b][d][s].
// ---------------------------------------------------------------------------
__global__ __launch_bounds__(192) void qkv_proj(
    const float* __restrict__ x,
    const float* __restrict__ Wq, const float* __restrict__ Wk,
    const float* __restrict__ Wv,
    __bf16* __restrict__ Q, __bf16* __restrict__ K, __bf16* __restrict__ Vt) {
  __shared__ float xs[16 * C_N];
  const int t = threadIdx.x;
  const int row0 = blockIdx.x * 16;               // flat row in [0, B*S)
  const float* xb = x + (size_t)row0 * C_N;
  for (int idx = t; idx < 16 * C_N; idx += 192) xs[idx] = xb[idx];
  __syncthreads();

  const int mat = t >> 6;                         // 0=Q 1=K 2=V (wave-aligned)
  const int d = t & 63;
  const float* W = (mat == 0) ? Wq : (mat == 1) ? Wk : Wv;

  float acc[16];
#pragma unroll
  for (int r = 0; r < 16; ++r) acc[r] = 0.f;

  for (int c = 0; c < C_N; c += 4) {
    const float w0 = W[(c + 0) * 64 + d];
    const float w1 = W[(c + 1) * 64 + d];
    const float w2 = W[(c + 2) * 64 + d];
    const float w3 = W[(c + 3) * 64 + d];
#pragma unroll
    for (int r = 0; r < 16; ++r) {
      const float4 xv = *reinterpret_cast<const float4*>(&xs[r * C_N + c]);
      acc[r] = fmaf(xv.x, w0, acc[r]);
      acc[r] = fmaf(xv.y, w1, acc[r]);
      acc[r] = fmaf(xv.z, w2, acc[r]);
      acc[r] = fmaf(xv.w, w3, acc[r]);
    }
  }

  if (mat == 2) {                                 // V -> transposed bf16
    const int b = row0 >> 11, s0 = row0 & (S_N - 1);
    __bf16* vp = Vt + ((size_t)b * D_N + d) * S_N + s0;
#pragma unroll
    for (int r = 0; r < 16; ++r) vp[r] = (__bf16)acc[r];
  } else {
    __bf16* outp = (mat == 0) ? Q : K;
    const float scl = (mat == 0) ? 0.125f : 1.0f;
#pragma unroll
    for (int r = 0; r < 16; ++r)
      outp[(size_t)(row0 + r) * 64 + d] = (__bf16)(acc[r] * scl);
  }
}

// ---------------------------------------------------------------------------
// Kernel 2a: partial column stats via MFMA. Grid (jb, ic, b); 4 waves.
// Wave w covers rows i0+16w..+15 per 64-row step; keeps private per-column
// (m,z) in registers (D col = lane&15; reduce over rows = shfl_xor 16/32).
// NO barriers. Partials per (b,jb,ic,wave): 32 per column.
// ---------------------------------------------------------------------------
__global__ __launch_bounds__(256) void col_part(
    const __bf16* __restrict__ Q, const __bf16* __restrict__ K,
    float* __restrict__ mP, float* __restrict__ zP) {
  const int jb = blockIdx.x, ic = blockIdx.y, b = blockIdx.z;
  const int j0 = jb * 64;
  const int t = threadIdx.x;
  const int iStart = max(j0, ic * (S_N / NCHUNK));
  const int iEnd = min(S_N, (ic + 1) * (S_N / NCHUNK));
  const size_t pbase = ((size_t)(b * 32 + jb) * NCHUNK + ic) * 4 * 64;

  if (iStart >= iEnd) {            // neutral partials (256 slots == 256 threads)
    mP[pbase + t] = NEG_BIG;
    zP[pbase + t] = 0.f;
    return;
  }

  const int w = t >> 6, lane = t & 63, lr = lane & 15, lg = lane >> 4;
  const __bf16* Qb = Q + (size_t)b * S_N * 64;
  const __bf16* Kb = K + (size_t)b * S_N * 64;

  bf16x8 bk[4][2];
#pragma unroll
  for (int jt = 0; jt < 4; ++jt) {
    bk[jt][0] = ldfrag(Kb + (size_t)(j0 + jt * 16 + lr) * 64 + lg * 8);
    bk[jt][1] = ldfrag(Kb + (size_t)(j0 + jt * 16 + lr) * 64 + 32 + lg * 8);
  }

  float m4[4], z4[4];
#pragma unroll
  for (int jt = 0; jt < 4; ++jt) { m4[jt] = NEG_BIG; z4[jt] = 0.f; }

  for (int i0 = iStart; i0 < iEnd; i0 += 64) {
    const int ri = i0 + w * 16 + lr;
    const bf16x8 aq0 = ldfrag(Qb + (size_t)ri * 64 + lg * 8);
    const bf16x8 aq1 = ldfrag(Qb + (size_t)ri * 64 + 32 + lg * 8);
    const int ibase = i0 + w * 16 + lg * 4;       // D-row base for this lane
    const bool diag = (i0 == j0);
#pragma unroll
    for (int jt = 0; jt < 4; ++jt) {
      f32x4 s = {0.f, 0.f, 0.f, 0.f};
      s = __builtin_amdgcn_mfma_f32_16x16x32_bf16(aq0, bk[jt][0], s, 0, 0, 0);
      s = __builtin_amdgcn_mfma_f32_16x16x32_bf16(aq1, bk[jt][1], s, 0, 0, 0);
      const int jg = j0 + jt * 16 + lr;           // D col = lane&15
      if (diag) {
#pragma unroll
        for (int r = 0; r < 4; ++r)
          if (ibase + r < jg) s[r] = NEG_BIG;
      }
      float tm = fmaxf(fmaxf(s[0], s[1]), fmaxf(s[2], s[3]));
      tm = fmaxf(tm, __shfl_xor(tm, 16));
      tm = fmaxf(tm, __shfl_xor(tm, 32));
      const float mo = m4[jt];
      const float mn = fmaxf(mo, tm);
      float es = __expf(s[0] - mn) + __expf(s[1] - mn) +
                 __expf(s[2] - mn) + __expf(s[3] - mn);
      es += __shfl_xor(es, 16);
      es += __shfl_xor(es, 32);
      z4[jt] = z4[jt] * __expf(mo - mn) + es;
      m4[jt] = mn;
    }
  }

  if (lg == 0) {                                  // one copy per column
#pragma unroll
    for (int jt = 0; jt < 4; ++jt) {
      mP[pbase + w * 64 + jt * 16 + lr] = m4[jt];
      zP[pbase + w * 64 + jt * 16 + lr] = z4[jt];
    }
  }
}

// ---------------------------------------------------------------------------
// Kernel 2b: merge the NCHUNK*4 partials per column -> m, 1/Z.
// ---------------------------------------------------------------------------
__global__ __launch_bounds__(256) void col_reduce(
    const float* __restrict__ mP, const float* __restrict__ zP,
    float* __restrict__ mC, float* __restrict__ rZ) {
  const int idx = blockIdx.x * 256 + threadIdx.x;  // b*S + j
  const int b = idx >> 11;
  const int j = idx & (S_N - 1);
  const int jb = j >> 6, jr = j & 63;
  const size_t base = (size_t)(b * 32 + jb) * NCHUNK * 4 * 64 + jr;

  float m = NEG_BIG;
#pragma unroll 8
  for (int p = 0; p < NCHUNK * 4; ++p) m = fmaxf(m, mP[base + (size_t)p * 64]);
  float z = 0.f;
#pragma unroll 8
  for (int p = 0; p < NCHUNK * 4; ++p)
    z += zP[base + (size_t)p * 64] * __expf(mP[base + (size_t)p * 64] - m);

  mC[idx] = m;
  rZ[idx] = 1.0f / z;
}

// ---------------------------------------------------------------------------
// Kernel 3: output pass via MFMA. Grid (jchunk, ib, b); 4 independent waves,
// each owning a 16-row strip. P staged per-wave in LDS (no barriers).
// B-operand of PV read from transposed V. atomicAdd f32 partials over jchunks.
// ---------------------------------------------------------------------------
__global__ __launch_bounds__(256) void attn_out(
    const __bf16* __restrict__ Q, const __bf16* __restrict__ K,
    const __bf16* __restrict__ Vt, const float* __restrict__ mC,
    const float* __restrict__ rZ, float* __restrict__ out) {
  const int b = blockIdx.z, ib = blockIdx.y;
  const int jb_lo = blockIdx.x * JCH;
  if (jb_lo > ib) return;
  const int jb_hi = min(jb_lo + JCH, ib + 1);

  const int t = threadIdx.x;
  const int w = t >> 6, lane = t & 63, lr = lane & 15, lg = lane >> 4;
  const int i0 = ib * 64;

  __shared__ __align__(16) __bf16 P_lds[4][16][72];  // per-wave 16x64 (+pad 8)

  const __bf16* Qb = Q + (size_t)b * S_N * 64;
  const __bf16* Kb = K + (size_t)b * S_N * 64;
  const __bf16* Vb = Vt + (size_t)b * D_N * S_N;

  const int ri = i0 + w * 16 + lr;
  const bf16x8 aq0 = ldfrag(Qb + (size_t)ri * 64 + lg * 8);
  const bf16x8 aq1 = ldfrag(Qb + (size_t)ri * 64 + 32 + lg * 8);
  const int ibase = i0 + w * 16 + lg * 4;          // D-row base

  f32x4 o[4];
#pragma unroll
  for (int dt = 0; dt < 4; ++dt) o[dt] = {0.f, 0.f, 0.f, 0.f};

  for (int jb = jb_lo; jb < jb_hi; ++jb) {
    const int j0 = jb * 64;
    // ---- scores + P (causal mask folded in; always-on compare is cheap) ----
#pragma unroll
    for (int jt = 0; jt < 4; ++jt) {
      const bf16x8 bk0 = ldfrag(Kb + (size_t)(j0 + jt * 16 + lr) * 64 + lg * 8);
      const bf16x8 bk1 = ldfrag(Kb + (size_t)(j0 + jt * 16 + lr) * 64 + 32 + lg * 8);
      f32x4 s = {0.f, 0.f, 0.f, 0.f};
      s = __builtin_amdgcn_mfma_f32_16x16x32_bf16(aq0, bk0, s, 0, 0, 0);
      s = __builtin_amdgcn_mfma_f32_16x16x32_bf16(aq1, bk1, s, 0, 0, 0);
      const int jg = j0 + jt * 16 + lr;            // D col
      const float mj = mC[(size_t)b * S_N + jg];
      const float rz = rZ[(size_t)b * S_N + jg];
#pragma unroll
      for (int r = 0; r < 4; ++r) {
        const float pv = (jg <= ibase + r) ? __expf(s[r] - mj) * rz : 0.f;
        P_lds[w][lg * 4 + r][jt * 16 + lr] = (__bf16)pv;
      }
    }
    // ---- PV: A = P (own strip, own writes; in-order DS pipe, no barrier) ----
    const bf16x8 ap0 = ldfrag(&P_lds[w][lr][lg * 8]);
    const bf16x8 ap1 = ldfrag(&P_lds[w][lr][32 + lg * 8]);
#pragma unroll
    for (int dt = 0; dt < 4; ++dt) {
      const bf16x8 bv0 = ldfrag(Vb + (size_t)(dt * 16 + lr) * S_N + j0 + lg * 8);
      const bf16x8 bv1 = ldfrag(Vb + (size_t)(dt * 16 + lr) * S_N + j0 + 32 + lg * 8);
      o[dt] = __builtin_amdgcn_mfma_f32_16x16x32_bf16(ap0, bv0, o[dt], 0, 0, 0);
      o[dt] = __builtin_amdgcn_mfma_f32_16x16x32_bf16(ap1, bv1, o[dt], 0, 0, 0);
    }
  }

  float* ob = out + (size_t)b * S_N * D_N;
#pragma unroll
  for (int dt = 0; dt < 4; ++dt)
#pragma unroll
    for (int r = 0; r < 4; ++r)
      atomicAdd(&ob[(size_t)(ibase + r) * D_N + dt * 16 + lr], o[dt][r]);
}

extern "C" void kernel_launch(void* const* d_in, const int* in_sizes, int n_in,
                              void* d_out, int out_size, void* d_ws, size_t ws_size,
                              hipStream_t stream) {
  (void)in_sizes; (void)n_in; (void)ws_size;
  const float* x  = (const float*)d_in[0];
  const float* Wq = (const float*)d_in[1];
  const float* Wk = (const float*)d_in[2];
  const float* Wv = (const float*)d_in[3];
  float* out = (float*)d_out;

  __bf16* Qb = (__bf16*)d_ws;                         // [B*S][64] pre-scaled
  __bf16* Kb = Qb + (size_t)B_N * S_N * D_N;          // [B*S][64]
  __bf16* Vt = Kb + (size_t)B_N * S_N * D_N;          // [B][64][S] transposed
  float* mC = (float*)(Vt + (size_t)B_N * S_N * D_N); // [B,S]
  float* rZ = mC + (size_t)B_N * S_N;                 // [B,S]
  float* mP = rZ + (size_t)B_N * S_N;                 // [B,32,NCHUNK,4,64]
  float* zP = mP + (size_t)B_N * 32 * NCHUNK * 4 * 64;

  hipMemsetAsync(d_out, 0, (size_t)out_size * sizeof(float), stream);

  qkv_proj<<<dim3(B_N * S_N / 16), dim3(192), 0, stream>>>(x, Wq, Wk, Wv, Qb, Kb, Vt);
  col_part<<<dim3(S_N / 64, NCHUNK, B_N), dim3(256), 0, stream>>>(Qb, Kb, mP, zP);
  col_reduce<<<dim3(B_N * S_N / 256), dim3(256), 0, stream>>>(mP, zP, mC, rZ);
  attn_out<<<dim3(S_N / 64 / JCH, S_N / 64, B_N), dim3(256), 0, stream>>>(
      Qb, Kb, Vt, mC, rZ, out);
}

// Round 7
// 137.978 us; speedup vs baseline: 2.9213x; 1.2841x over previous
//
#include <hip/hip_runtime.h>
#include <hip/hip_bf16.h>
#include <math.h>

#define B_N 8
#define S_N 2048
#define C_N 384
#define D_N 64
#define NCHUNK 8          // i-chunks for col_part (256 rows each)
#define JCH 4             // jb blocks per attn_out WG
#define NEG_BIG (-1e30f)

typedef __bf16 bf16x8 __attribute__((ext_vector_type(8)));
typedef float f32x4 __attribute__((ext_vector_type(4)));

static __device__ __forceinline__ bf16x8 ldfrag(const __bf16* p) {
  return *reinterpret_cast<const bf16x8*>(p);
}

// ---------------------------------------------------------------------------
// Kernel 0: weight prep. Wt[m][d][c] = (bf16) W_m[c][d].  (3*64*384 threads)
// Coalesced writes; scattered reads are L2-resident after first touch.
// ---------------------------------------------------------------------------
__global__ __launch_bounds__(256) void w_prep(
    const float* __restrict__ Wq, const float* __restrict__ Wk,
    const float* __restrict__ Wv, __bf16* __restrict__ Wt) {
  const int idx = blockIdx.x * 256 + threadIdx.x;   // [0, 3*64*384)
  const int m = idx / (64 * C_N);
  const int r = idx % (64 * C_N);
  const int d = r / C_N;
  const int c = r % C_N;
  const float* W = (m == 0) ? Wq : (m == 1) ? Wk : Wv;
  Wt[idx] = (__bf16)W[c * 64 + d];
}

// ---------------------------------------------------------------------------
// Kernel 1: QKV projection via MFMA. 384 threads = 6 waves; wave w handles
// mat = w>>1 (0=Q,1=K,2=V), row-half rh = w&1 (16 rows). 32 x-rows per block.
// A-frag: x rows, f32->bf16 inline (Q pre-scaled 0.125). B-frag: Wt rows.
// V routed through a small LDS tile for a coalesced transposed store.
// ---------------------------------------------------------------------------
__global__ __launch_bounds__(384) void qkv_mfma(
    const float* __restrict__ x, const __bf16* __restrict__ Wt,
    __bf16* __restrict__ Q, __bf16* __restrict__ K, __bf16* __restrict__ Vt) {
  const int t = threadIdx.x;
  const int w = t >> 6, lane = t & 63, lr = lane & 15, lg = lane >> 4;
  const int mat = w >> 1, rh = w & 1;
  const int row0 = blockIdx.x * 32;                 // flat row in [0, B*S)
  const int ri = row0 + rh * 16 + lr;

  __shared__ __bf16 vtile[32][66];                  // V block, padded

  const float scl = (mat == 0) ? 0.125f : 1.0f;
  const float* xr = x + (size_t)ri * C_N;
  const __bf16* Wm = Wt + (size_t)mat * 64 * C_N;

  f32x4 acc[4];
#pragma unroll
  for (int nt = 0; nt < 4; ++nt) acc[nt] = {0.f, 0.f, 0.f, 0.f};

#pragma unroll 4
  for (int kk = 0; kk < C_N / 32; ++kk) {
    const float4 xa = *reinterpret_cast<const float4*>(xr + kk * 32 + lg * 8);
    const float4 xb = *reinterpret_cast<const float4*>(xr + kk * 32 + lg * 8 + 4);
    bf16x8 a;
    a[0] = (__bf16)(xa.x * scl); a[1] = (__bf16)(xa.y * scl);
    a[2] = (__bf16)(xa.z * scl); a[3] = (__bf16)(xa.w * scl);
    a[4] = (__bf16)(xb.x * scl); a[5] = (__bf16)(xb.y * scl);
    a[6] = (__bf16)(xb.z * scl); a[7] = (__bf16)(xb.w * scl);
#pragma unroll
    for (int nt = 0; nt < 4; ++nt) {
      const bf16x8 bw = ldfrag(Wm + (size_t)(nt * 16 + lr) * C_N + kk * 32 + lg * 8);
      acc[nt] = __builtin_amdgcn_mfma_f32_16x16x32_bf16(a, bw, acc[nt], 0, 0, 0);
    }
  }

  // D layout: col = lane&15 (n), row = lg*4 + r (within 16-row half)
  if (mat < 2) {
    __bf16* outp = (mat == 0) ? Q : K;
#pragma unroll
    for (int nt = 0; nt < 4; ++nt)
#pragma unroll
      for (int r = 0; r < 4; ++r)
        outp[(size_t)(row0 + rh * 16 + lg * 4 + r) * 64 + nt * 16 + lr] =
            (__bf16)acc[nt][r];
  } else {
#pragma unroll
    for (int nt = 0; nt < 4; ++nt)
#pragma unroll
      for (int r = 0; r < 4; ++r)
        vtile[rh * 16 + lg * 4 + r][nt * 16 + lr] = (__bf16)acc[nt][r];
  }
  __syncthreads();

  // cooperative transposed V store: Vt[b][d][s0..s0+31]
  const int b = row0 >> 11, s0 = row0 & (S_N - 1);
  for (int idx = t; idx < 64 * 32; idx += 384) {
    const int d = idx >> 5, s2 = idx & 31;
    Vt[((size_t)b * D_N + d) * S_N + s0 + s2] = vtile[s2][d];
  }
}

// ---------------------------------------------------------------------------
// Kernel 2a: partial column stats via MFMA (unchanged from R6).
// ---------------------------------------------------------------------------
__global__ __launch_bounds__(256) void col_part(
    const __bf16* __restrict__ Q, const __bf16* __restrict__ K,
    float* __restrict__ mP, float* __restrict__ zP) {
  const int jb = blockIdx.x, ic = blockIdx.y, b = blockIdx.z;
  const int j0 = jb * 64;
  const int t = threadIdx.x;
  const int iStart = max(j0, ic * (S_N / NCHUNK));
  const int iEnd = min(S_N, (ic + 1) * (S_N / NCHUNK));
  const size_t pbase = ((size_t)(b * 32 + jb) * NCHUNK + ic) * 4 * 64;

  if (iStart >= iEnd) {            // neutral partials (256 slots == 256 threads)
    mP[pbase + t] = NEG_BIG;
    zP[pbase + t] = 0.f;
    return;
  }

  const int w = t >> 6, lane = t & 63, lr = lane & 15, lg = lane >> 4;
  const __bf16* Qb = Q + (size_t)b * S_N * 64;
  const __bf16* Kb = K + (size_t)b * S_N * 64;

  bf16x8 bk[4][2];
#pragma unroll
  for (int jt = 0; jt < 4; ++jt) {
    bk[jt][0] = ldfrag(Kb + (size_t)(j0 + jt * 16 + lr) * 64 + lg * 8);
    bk[jt][1] = ldfrag(Kb + (size_t)(j0 + jt * 16 + lr) * 64 + 32 + lg * 8);
  }

  float m4[4], z4[4];
#pragma unroll
  for (int jt = 0; jt < 4; ++jt) { m4[jt] = NEG_BIG; z4[jt] = 0.f; }

  for (int i0 = iStart; i0 < iEnd; i0 += 64) {
    const int ri = i0 + w * 16 + lr;
    const bf16x8 aq0 = ldfrag(Qb + (size_t)ri * 64 + lg * 8);
    const bf16x8 aq1 = ldfrag(Qb + (size_t)ri * 64 + 32 + lg * 8);
    const int ibase = i0 + w * 16 + lg * 4;       // D-row base for this lane
    const bool diag = (i0 == j0);
#pragma unroll
    for (int jt = 0; jt < 4; ++jt) {
      f32x4 s = {0.f, 0.f, 0.f, 0.f};
      s = __builtin_amdgcn_mfma_f32_16x16x32_bf16(aq0, bk[jt][0], s, 0, 0, 0);
      s = __builtin_amdgcn_mfma_f32_16x16x32_bf16(aq1, bk[jt][1], s, 0, 0, 0);
      const int jg = j0 + jt * 16 + lr;           // D col = lane&15
      if (diag) {
#pragma unroll
        for (int r = 0; r < 4; ++r)
          if (ibase + r < jg) s[r] = NEG_BIG;
      }
      float tm = fmaxf(fmaxf(s[0], s[1]), fmaxf(s[2], s[3]));
      tm = fmaxf(tm, __shfl_xor(tm, 16));
      tm = fmaxf(tm, __shfl_xor(tm, 32));
      const float mo = m4[jt];
      const float mn = fmaxf(mo, tm);
      float es = __expf(s[0] - mn) + __expf(s[1] - mn) +
                 __expf(s[2] - mn) + __expf(s[3] - mn);
      es += __shfl_xor(es, 16);
      es += __shfl_xor(es, 32);
      z4[jt] = z4[jt] * __expf(mo - mn) + es;
      m4[jt] = mn;
    }
  }

  if (lg == 0) {                                  // one copy per column
#pragma unroll
    for (int jt = 0; jt < 4; ++jt) {
      mP[pbase + w * 64 + jt * 16 + lr] = m4[jt];
      zP[pbase + w * 64 + jt * 16 + lr] = z4[jt];
    }
  }
}

// ---------------------------------------------------------------------------
// Kernel 2b: merge the NCHUNK*4 partials per column -> m, 1/Z.
// ---------------------------------------------------------------------------
__global__ __launch_bounds__(256) void col_reduce(
    const float* __restrict__ mP, const float* __restrict__ zP,
    float* __restrict__ mC, float* __restrict__ rZ) {
  const int idx = blockIdx.x * 256 + threadIdx.x;  // b*S + j
  const int b = idx >> 11;
  const int j = idx & (S_N - 1);
  const int jb = j >> 6, jr = j & 63;
  const size_t base = (size_t)(b * 32 + jb) * NCHUNK * 4 * 64 + jr;

  float m = NEG_BIG;
#pragma unroll 8
  for (int p = 0; p < NCHUNK * 4; ++p) m = fmaxf(m, mP[base + (size_t)p * 64]);
  float z = 0.f;
#pragma unroll 8
  for (int p = 0; p < NCHUNK * 4; ++p)
    z += zP[base + (size_t)p * 64] * __expf(mP[base + (size_t)p * 64] - m);

  mC[idx] = m;
  rZ[idx] = 1.0f / z;
}

// ---------------------------------------------------------------------------
// Kernel 3: output pass via MFMA (unchanged from R6).
// ---------------------------------------------------------------------------
__global__ __launch_bounds__(256) void attn_out(
    const __bf16* __restrict__ Q, const __bf16* __restrict__ K,
    const __bf16* __restrict__ Vt, const float* __restrict__ mC,
    const float* __restrict__ rZ, float* __restrict__ out) {
  const int b = blockIdx.z, ib = blockIdx.y;
  const int jb_lo = blockIdx.x * JCH;
  if (jb_lo > ib) return;
  const int jb_hi = min(jb_lo + JCH, ib + 1);

  const int t = threadIdx.x;
  const int w = t >> 6, lane = t & 63, lr = lane & 15, lg = lane >> 4;
  const int i0 = ib * 64;

  __shared__ __align__(16) __bf16 P_lds[4][16][72];  // per-wave 16x64 (+pad 8)

  const __bf16* Qb = Q + (size_t)b * S_N * 64;
  const __bf16* Kb = K + (size_t)b * S_N * 64;
  const __bf16* Vb = Vt + (size_t)b * D_N * S_N;

  const int ri = i0 + w * 16 + lr;
  const bf16x8 aq0 = ldfrag(Qb + (size_t)ri * 64 + lg * 8);
  const bf16x8 aq1 = ldfrag(Qb + (size_t)ri * 64 + 32 + lg * 8);
  const int ibase = i0 + w * 16 + lg * 4;          // D-row base

  f32x4 o[4];
#pragma unroll
  for (int dt = 0; dt < 4; ++dt) o[dt] = {0.f, 0.f, 0.f, 0.f};

  for (int jb = jb_lo; jb < jb_hi; ++jb) {
    const int j0 = jb * 64;
    // ---- scores + P (causal mask folded in) ----
#pragma unroll
    for (int jt = 0; jt < 4; ++jt) {
      const bf16x8 bk0 = ldfrag(Kb + (size_t)(j0 + jt * 16 + lr) * 64 + lg * 8);
      const bf16x8 bk1 = ldfrag(Kb + (size_t)(j0 + jt * 16 + lr) * 64 + 32 + lg * 8);
      f32x4 s = {0.f, 0.f, 0.f, 0.f};
      s = __builtin_amdgcn_mfma_f32_16x16x32_bf16(aq0, bk0, s, 0, 0, 0);
      s = __builtin_amdgcn_mfma_f32_16x16x32_bf16(aq1, bk1, s, 0, 0, 0);
      const int jg = j0 + jt * 16 + lr;            // D col
      const float mj = mC[(size_t)b * S_N + jg];
      const float rz = rZ[(size_t)b * S_N + jg];
#pragma unroll
      for (int r = 0; r < 4; ++r) {
        const float pv = (jg <= ibase + r) ? __expf(s[r] - mj) * rz : 0.f;
        P_lds[w][lg * 4 + r][jt * 16 + lr] = (__bf16)pv;
      }
    }
    // ---- PV: A = P (own strip, own writes; in-order DS pipe, no barrier) ----
    const bf16x8 ap0 = ldfrag(&P_lds[w][lr][lg * 8]);
    const bf16x8 ap1 = ldfrag(&P_lds[w][lr][32 + lg * 8]);
#pragma unroll
    for (int dt = 0; dt < 4; ++dt) {
      const bf16x8 bv0 = ldfrag(Vb + (size_t)(dt * 16 + lr) * S_N + j0 + lg * 8);
      const bf16x8 bv1 = ldfrag(Vb + (size_t)(dt * 16 + lr) * S_N + j0 + 32 + lg * 8);
      o[dt] = __builtin_amdgcn_mfma_f32_16x16x32_bf16(ap0, bv0, o[dt], 0, 0, 0);
      o[dt] = __builtin_amdgcn_mfma_f32_16x16x32_bf16(ap1, bv1, o[dt], 0, 0, 0);
    }
  }

  float* ob = out + (size_t)b * S_N * D_N;
#pragma unroll
  for (int dt = 0; dt < 4; ++dt)
#pragma unroll
    for (int r = 0; r < 4; ++r)
      atomicAdd(&ob[(size_t)(ibase + r) * D_N + dt * 16 + lr], o[dt][r]);
}

extern "C" void kernel_launch(void* const* d_in, const int* in_sizes, int n_in,
                              void* d_out, int out_size, void* d_ws, size_t ws_size,
                              hipStream_t stream) {
  (void)in_sizes; (void)n_in; (void)ws_size;
  const float* x  = (const float*)d_in[0];
  const float* Wq = (const float*)d_in[1];
  const float* Wk = (const float*)d_in[2];
  const float* Wv = (const float*)d_in[3];
  float* out = (float*)d_out;

  __bf16* Qb = (__bf16*)d_ws;                         // [B*S][64] pre-scaled
  __bf16* Kb = Qb + (size_t)B_N * S_N * D_N;          // [B*S][64]
  __bf16* Vt = Kb + (size_t)B_N * S_N * D_N;          // [B][64][S] transposed
  float* mC = (float*)(Vt + (size_t)B_N * S_N * D_N); // [B,S]
  float* rZ = mC + (size_t)B_N * S_N;                 // [B,S]
  float* mP = rZ + (size_t)B_N * S_N;                 // [B,32,NCHUNK,4,64]
  float* zP = mP + (size_t)B_N * 32 * NCHUNK * 4 * 64;
  __bf16* Wt = (__bf16*)(zP + (size_t)B_N * 32 * NCHUNK * 4 * 64); // [3][64][384]

  hipMemsetAsync(d_out, 0, (size_t)out_size * sizeof(float), stream);

  w_prep<<<dim3(3 * 64 * C_N / 256), dim3(256), 0, stream>>>(Wq, Wk, Wv, Wt);
  qkv_mfma<<<dim3(B_N * S_N / 32), dim3(384), 0, stream>>>(x, Wt, Qb, Kb, Vt);
  col_part<<<dim3(S_N / 64, NCHUNK, B_N), dim3(256), 0, stream>>>(Qb, Kb, mP, zP);
  col_reduce<<<dim3(B_N * S_N / 256), dim3(256), 0, stream>>>(mP, zP, mC, rZ);
  attn_out<<<dim3(S_N / 64 / JCH, S_N / 64, B_N), dim3(256), 0, stream>>>(
      Qb, Kb, Vt, mC, rZ, out);
}